// Round 1
// 114.863 us; speedup vs baseline: 1.0394x; 1.0394x over previous
//
#include <hip/hip_runtime.h>

// svPositionsAtT0: (B=64, N=63, 3)  f32
// svEncoding:      (B=64, N=63, 512) f32
// lengths:         (B=64,) i32
// out:             (B, 512, 28, 28) f32 = max(0, scatter-max of valid agent encodings)
#define NSV    63
#define HID    512
#define GW     28
#define GH     28
#define CELLS  (GW * GH)      // 784
#define HCHUNK 16             // h-values per block
#define NTHREADS 256
#define NQUADS (CELLS / 4)    // 196 float4 per h-row
#define EPAD   20             // padded enc_s row stride in floats (mult of 4 for b128)

// XOR-swizzle on ULL index: flip bits 2-3 with bits 4-5.
// Bijective within each 16-ULL group (784 = 49*16, always in range).
// Readers (lane t reads ULLs 4t..4t+3) land on 4-way instead of 16-way conflicts,
// and the 4 masks stay contiguous after the swizzle (j lives in bits 0-1).
__device__ __forceinline__ int swz(int u) { return u ^ (((u >> 4) & 3) << 2); }

__global__ __launch_bounds__(NTHREADS)
void scatter_grid_kernel(const float* __restrict__ pos,
                         const float* __restrict__ enc,
                         const int*   __restrict__ lengths,
                         float*       __restrict__ out) {
    const int b      = blockIdx.y;
    const int h_base = blockIdx.x * HCHUNK;
    const int t      = threadIdx.x;

    __shared__ unsigned long long mask_s[CELLS];      // per-cell agent bitmask (swizzled), 6.3 KB
    __shared__ float enc_s[NSV * EPAD + 4];           // [n][h] padded rows, ~5 KB

    // ---- zero the masks ----
    for (int c = t; c < CELLS; c += NTHREADS) mask_s[c] = 0ull;

    // ---- stage encoding slice: enc[b, n, h_base:h_base+16] (64B per agent) ----
    {
        const int n = t >> 2;        // 0..63
        const int q = t & 3;         // float4 within the 16-h slice
        if (n < NSV) {
            const float4 v = ((const float4*)(enc + ((size_t)b * NSV + n) * HID + h_base))[q];
            *(float4*)(enc_s + n * EPAD + q * 4) = v;   // EPAD%4==0 -> 16B aligned
        }
    }
    __syncthreads();   // mask zeroing must complete before atomicOr

    // ---- per-agent cell index + validity -> set bit in cell's mask ----
    if (t < NSV) {
        const float x = pos[((size_t)b * NSV + t) * 3 + 0];
        const float y = pos[((size_t)b * NSV + t) * 3 + 1];
        const int len = lengths[b];
        // exact replication of jnp: (x * 28) / 224 in f32, trunc toward zero
        const int xi = (int)(x * 28.0f / 224.0f);
        const int yi = (int)(y * 28.0f / 224.0f);
        if ((t < len) && (xi < GW) && (yi < GH)) {
            const int xc = min(max(xi, 0), GW - 1);
            const int yc = min(max(yi, 0), GH - 1);
            atomicOr(&mask_s[swz(xc * GH + yc)], 1ull << t);
        }
    }
    __syncthreads();

    // ---- writeout: thread t owns cells 4t..4t+3 for ALL 16 h values ----
    // Masks read ONCE into registers (vs 16x before); h-loop reuses them.
    if (t < NQUADS) {
        unsigned long long m0, m1, m2, m3;
        {
            const int base = swz(4 * t);   // contiguous run of 4 after swizzle
            const ulonglong2 a = *(const ulonglong2*)(mask_s + base);
            const ulonglong2 c = *(const ulonglong2*)(mask_s + base + 2);
            m0 = a.x; m1 = a.y; m2 = c.x; m3 = c.y;
        }

        float4* d4 = (float4*)(out + ((size_t)b * HID + h_base) * CELLS);

        #pragma unroll
        for (int hq = 0; hq < 4; ++hq) {
            // v0..v3: one float4 per h (hq*4+0 .. hq*4+3), components = the 4 cells
            float4 v0 = make_float4(0.f, 0.f, 0.f, 0.f);
            float4 v1 = v0, v2 = v0, v3 = v0;
            #pragma unroll
            for (int j = 0; j < 4; ++j) {
                unsigned long long mm = (j == 0) ? m0 : (j == 1) ? m1 : (j == 2) ? m2 : m3;
                while (mm) {
                    const int n = __ffsll(mm) - 1;
                    mm &= mm - 1;
                    const float4 e = *(const float4*)(enc_s + n * EPAD + hq * 4);
                    (&v0.x)[j] = fmaxf((&v0.x)[j], e.x);
                    (&v1.x)[j] = fmaxf((&v1.x)[j], e.y);
                    (&v2.x)[j] = fmaxf((&v2.x)[j], e.z);
                    (&v3.x)[j] = fmaxf((&v3.x)[j], e.w);
                }
            }
            // coalesced: lanes t..t+63 -> contiguous 1 KB per wave-store
            d4[(hq * 4 + 0) * NQUADS + t] = v0;
            d4[(hq * 4 + 1) * NQUADS + t] = v1;
            d4[(hq * 4 + 2) * NQUADS + t] = v2;
            d4[(hq * 4 + 3) * NQUADS + t] = v3;
        }
    }
}

extern "C" void kernel_launch(void* const* d_in, const int* in_sizes, int n_in,
                              void* d_out, int out_size, void* d_ws, size_t ws_size,
                              hipStream_t stream) {
    const float* pos     = (const float*)d_in[0];   // (B, 63, 3)
    const float* enc     = (const float*)d_in[1];   // (B, 63, 512)
    const int*   lengths = (const int*)d_in[2];     // (B,)
    float*       out     = (float*)d_out;           // (B, 512, 28, 28)

    const int B = in_sizes[2];                      // 64

    dim3 grid(HID / HCHUNK, B);                     // (32, 64) = 2048 blocks
    dim3 block(NTHREADS);
    scatter_grid_kernel<<<grid, block, 0, stream>>>(pos, enc, lengths, out);
}